// Round 18
// baseline (43.567 us; speedup 1.0000x reference)
//
#include <hip/hip_runtime.h>
#include <hip/hip_bf16.h>

// SelfContrastiveLoss: loss over E = exp(qn @ kn^T / T), B=8192, D=256.
// R18: q-streaming with K-resident registers (flip of R16, which streamed k
//      and paid the expensive colsum fold per tile). kf[4][2] loaded once per
//      wave; 8 q-tiles of 128 rows stream through. Cheap rowsum per tile,
//      colsum accumulated in cacc[] regs, expensive fold ONCE at end.
//      Zero LDS / zero barriers; 8 MFMA<->VALU alternation points per wave so
//      the 2 waves/SIMD overlap pipes (m114). 512 blocks = exactly 2/CU;
//      qc = lid&7 -> each XCD streams one qc (k 2MB + q 256KB L2-resident).
//
// ws layout: qp 2MB | kp 2MB | diag 32KB | RowP 2MB (64*NB) | ColP 512KB (16*NB)

#define NB 8192
#define ND 256

constexpr float EPS = 1e-5f;
// exp(x*20) == exp2(x * 20*log2(e))
constexpr float EXP2_SCALE = 28.853900817779268f;

typedef float f32x4 __attribute__((ext_vector_type(4)));
typedef int   i32x8 __attribute__((ext_vector_type(8)));

__device__ __forceinline__ float fast_exp2(float x) {
  float r;
  asm("v_exp_f32 %0, %1" : "=v"(r) : "v"(x));   // exact for |x| <= 126
  return r;
}

// packed layout (per 16-row group g, per matrix): 32B unit (ks, lane):
//   row g*16 + (lane&15), K-bytes ks*128 + (lane>>4)*32 .. +32, CONTIGUOUS.
// byte address = g*4096 + ks*2048 + lane*32.

// ------------- kernel 1: L2-normalize -> fp8 e4m3 packed, fp32 diag ----------
__global__ __launch_bounds__(1024) void norm_pack_kernel(
    const float* __restrict__ q, const float* __restrict__ k,
    uint* __restrict__ qp, uint* __restrict__ kp, float* __restrict__ diag,
    float* __restrict__ out) {
  __shared__ uint lq[16 * 68];   // stride 68 dwords: breaks 64-stride banks
  __shared__ uint lk[16 * 68];
  if (blockIdx.x == 0 && threadIdx.x == 0) out[0] = 0.f;  // loss accumulator

  const int w    = threadIdx.x >> 6;          // 0..15 row-in-group
  const int lane = threadIdx.x & 63;
  const int row  = blockIdx.x * 16 + w;
  const float4* q4 = reinterpret_cast<const float4*>(q + (size_t)row * ND);
  const float4* k4 = reinterpret_cast<const float4*>(k + (size_t)row * ND);
  float4 qv = q4[lane];
  float4 kv = k4[lane];
  float sq = qv.x * qv.x + qv.y * qv.y + qv.z * qv.z + qv.w * qv.w;
  float sk = kv.x * kv.x + kv.y * kv.y + kv.z * kv.z + kv.w * kv.w;
  float dp = qv.x * kv.x + qv.y * kv.y + qv.z * kv.z + qv.w * kv.w;
#pragma unroll
  for (int m = 1; m < 64; m <<= 1) {
    sq += __shfl_xor(sq, m);
    sk += __shfl_xor(sk, m);
    dp += __shfl_xor(dp, m);
  }
  const float iq = 1.0f / fmaxf(sqrtf(sq), 1e-12f);   // F.normalize eps
  const float ik = 1.0f / fmaxf(sqrtf(sk), 1e-12f);
  int dq = __builtin_amdgcn_cvt_pk_fp8_f32(qv.x * iq, qv.y * iq, 0, false);
  dq = __builtin_amdgcn_cvt_pk_fp8_f32(qv.z * iq, qv.w * iq, dq, true);
  int dk = __builtin_amdgcn_cvt_pk_fp8_f32(kv.x * ik, kv.y * ik, 0, false);
  dk = __builtin_amdgcn_cvt_pk_fp8_f32(kv.z * ik, kv.w * ik, dk, true);
  lq[w * 68 + lane] = (uint)dq;
  lk[w * 68 + lane] = (uint)dk;
  if (lane == 0) diag[row] = __expf(dp * iq * ik * 20.0f);  // exact fp32 diag
  __syncthreads();

  // packed write: thread t<512 handles one 16B half of one 32B unit.
  const int t = threadIdx.x;
  if (t < 512) {
    const int tt = t & 255;
    const int u  = tt >> 1;           // unit 0..127 (= ks*64 + lane)
    const int h  = tt & 1;            // 16B half
    const int ul = u & 63;            // unit lane
    const int ks = u >> 6;
    const int src_dw = (ul & 15) * 68 + ks * 32 + (ul >> 4) * 8 + h * 4;
    const uint* Ls = (t < 256) ? lq : lk;
    uint4 v = *reinterpret_cast<const uint4*>(&Ls[src_dw]);
    uint* dst = (t < 256) ? qp : kp;
    reinterpret_cast<uint4*>(dst)[(size_t)blockIdx.x * 256 + tt] = v;
  }
}

// ------------- kernel 2: q-streaming MX-fp8 MFMA GEMM + exp + partials -------
// Block: 128 kcols (kb) x 1024 qrows (qc, 8 tiles of 128). 4 waves
// (2 wq x 2 wk); per tile wave computes 64q x 64k (acc[4][4]).
// TRANSPOSED: acc = mfma(K, Q): at lane (l15,lhi), frag (kg,qg), elem j2:
//   S[qrow = qbase+wq*64+qg*16+l15][kcol = kb*128+wk*64+kg*16+lhi*4+j2]
__global__ __launch_bounds__(256, 2) void gemm_exp_reduce_kernel(
    const uint* __restrict__ qp, const uint* __restrict__ kp,
    float* __restrict__ RowP, float* __restrict__ ColP) {
  const int tid  = threadIdx.x;
  const int lane = tid & 63;
  const int wave = tid >> 6;
  const int wq = wave >> 1;           // 0..1  (which 64 q-rows of the tile)
  const int wk = wave & 1;            // 0..1  (which 64 kcols)
  const int l15 = lane & 15;
  const int lhi = lane >> 4;

  // 512 blocks: qc = lid&7 (same-qc blocks land on one XCD), kb = lid>>3
  const int lid = blockIdx.x;
  const int qc  = lid & 7;             // 0..7  (1024-row q chunk)
  const int kb  = lid >> 3;            // 0..63 (128-col k block)

  const i32x8* qp8 = reinterpret_cast<const i32x8*>(qp);
  const i32x8* kp8 = reinterpret_cast<const i32x8*>(kp);

  // ---- K operand: loaded ONCE, resident 64 VGPRs ----
  const int kg0 = kb * 8 + wk * 4;
  i32x8 kf[4][2];
#pragma unroll
  for (int kg = 0; kg < 4; ++kg)
#pragma unroll
    for (int ks = 0; ks < 2; ++ks)
      kf[kg][ks] = kp8[(size_t)(kg0 + kg) * 128 + ks * 64 + lane];

  f32x4 cacc[4] = {};                  // colsum accumulators [kg][j2]

  const bool b0 = (l15 & 1), b1 = (l15 & 2), b2 = (l15 & 4), b3 = (l15 & 8);

  for (int t = 0; t < 8; ++t) {
    const int qg0 = qc * 64 + t * 8 + wq * 4;
    f32x4 acc[4][4];   // [kg][qg]
#pragma unroll
    for (int kg = 0; kg < 4; ++kg)
#pragma unroll
      for (int qg = 0; qg < 4; ++qg)
        acc[kg][qg] = (f32x4){0.f, 0.f, 0.f, 0.f};

#pragma unroll
    for (int ks = 0; ks < 2; ++ks) {
#pragma unroll
      for (int qg = 0; qg < 4; ++qg) {
        const i32x8 qf = qp8[(size_t)(qg0 + qg) * 128 + ks * 64 + lane];
#pragma unroll
        for (int kg = 0; kg < 4; ++kg)
          // fp8 x fp8, unity e8m0 scales (0x7F = 2^0); A=K, B=Q (transposed)
          acc[kg][qg] = __builtin_amdgcn_mfma_scale_f32_16x16x128_f8f6f4(
              kf[kg][ks], qf, acc[kg][qg], 0, 0, 0, 0x7F7F7F7F, 0, 0x7F7F7F7F);
      }
    }

    // ---- E = exp2(S*scale): raw v_exp_f32 ----
#pragma unroll
    for (int kg = 0; kg < 4; ++kg)
#pragma unroll
      for (int qg = 0; qg < 4; ++qg)
#pragma unroll
        for (int j2 = 0; j2 < 4; ++j2)
          acc[kg][qg][j2] = fast_exp2(acc[kg][qg][j2] * EXP2_SCALE);

    // ---- rowsums (cheap, per tile): in-thread over kg,j2; fold over lhi ----
    float rs[4];
#pragma unroll
    for (int qg = 0; qg < 4; ++qg) {
      f32x4 s4 = (acc[0][qg] + acc[1][qg]) + (acc[2][qg] + acc[3][qg]);
      float v = (s4[0] + s4[1]) + (s4[2] + s4[3]);
      v += __shfl_xor(v, 16);
      v += __shfl_xor(v, 32);
      rs[qg] = v;   // 64-col sum for row (qg,l15), replicated over lhi
    }
    {
      const float val = (lhi == 0) ? rs[0] : (lhi == 1) ? rs[1]
                        : (lhi == 2) ? rs[2] : rs[3];
      // wk=0/1 write different partial slots for the same rows
      RowP[(size_t)(kb * 2 + wk) * NB + qc * 1024 + t * 128 + wq * 64 +
           lhi * 16 + l15] = val;
    }

    // ---- colsums: accumulate into cacc (fold deferred to end) ----
#pragma unroll
    for (int kg = 0; kg < 4; ++kg)
      cacc[kg] += (acc[kg][0] + acc[kg][1]) + (acc[kg][2] + acc[kg][3]);
  }

  // ---- colsum 4-stage fold (R13-verified), ONCE ----
  float c[4][4];
#pragma unroll
  for (int kg = 0; kg < 4; ++kg)
#pragma unroll
    for (int j2 = 0; j2 < 4; ++j2)
      c[kg][j2] = cacc[kg][j2];
  float d[4][2];
#pragma unroll
  for (int kg = 0; kg < 4; ++kg) {
#pragma unroll
    for (int jh = 0; jh < 2; ++jh) {
      float t = b0 ? c[kg][jh * 2] : c[kg][jh * 2 + 1];
      float u = __shfl_xor(t, 1);
      d[kg][jh] = (b0 ? c[kg][jh * 2 + 1] : c[kg][jh * 2]) + u;
    }
  }
  float e[4];
#pragma unroll
  for (int kg = 0; kg < 4; ++kg) {
    float t = b1 ? d[kg][0] : d[kg][1];
    float u = __shfl_xor(t, 2);
    e[kg] = (b1 ? d[kg][1] : d[kg][0]) + u;
  }
  float g01, g23;
  {
    float t, u;
    t = b2 ? e[0] : e[1]; u = __shfl_xor(t, 4); g01 = (b2 ? e[1] : e[0]) + u;
    t = b2 ? e[2] : e[3]; u = __shfl_xor(t, 4); g23 = (b2 ? e[3] : e[2]) + u;
  }
  float f;
  {
    float t = b3 ? g01 : g23;
    float u = __shfl_xor(t, 8);
    f = (b3 ? g23 : g01) + u;
  }
  // lane holds kcol: kb*128 + wk*64 + (l15>>2)*16 + lhi*4 + (l15&3)
  ColP[(size_t)(qc * 2 + wq) * NB + kb * 128 + wk * 64 +
       (l15 >> 2) * 16 + lhi * 4 + (l15 & 3)] = f;
}

// ---------------- kernel 3: sum partials + final scalar loss ----------------
// RowP: 128 partials/row (64 kb x 2 wk); ColP: 16 partials/col (8 qc x 2 wq).
__global__ __launch_bounds__(256) void loss_kernel(
    const float* __restrict__ diag, const float* __restrict__ RowP,
    const float* __restrict__ ColP, float* __restrict__ out) {
  const int i = blockIdx.x * 256 + threadIdx.x;   // 32 blocks x 256 = 8192
  float rs = 0.f, cs = 0.f;
#pragma unroll 8
  for (int j = 0; j < 128; ++j) rs += RowP[(size_t)j * NB + i];
#pragma unroll 4
  for (int j = 0; j < 16; ++j) cs += ColP[(size_t)j * NB + i];
  const float d = diag[i];
  float acc = -__logf(d / rs + EPS) - __logf(d / cs + EPS);
#pragma unroll
  for (int m = 1; m < 64; m <<= 1) acc += __shfl_xor(acc, m);
  __shared__ float ls[4];
  const int wave = threadIdx.x >> 6;
  if ((threadIdx.x & 63) == 0) ls[wave] = acc;
  __syncthreads();
  if (threadIdx.x == 0)
    atomicAdd(out, (ls[0] + ls[1] + ls[2] + ls[3]) * (1.0f / NB));
}

extern "C" void kernel_launch(void* const* d_in, const int* in_sizes, int n_in,
                              void* d_out, int out_size, void* d_ws, size_t ws_size,
                              hipStream_t stream) {
  const float* q = (const float*)d_in[0];
  const float* k = (const float*)d_in[1];
  char* ws = (char*)d_ws;
  uint*  qp   = (uint*)ws;                                      // 2 MB packed
  uint*  kp   = (uint*)(ws + (size_t)NB * ND);                  // 2 MB packed
  float* diag = (float*)(ws + (size_t)2 * NB * ND);             // 32 KB
  float* RowP = diag + NB;                                      // 2 MB (128*NB)
  float* ColP = RowP + 128 * NB;                                // 512 KB (16*NB)
  float* out  = (float*)d_out;

  norm_pack_kernel<<<NB / 16, 1024, 0, stream>>>(q, k, qp, kp, diag, out);
  gemm_exp_reduce_kernel<<<512, 256, 0, stream>>>(qp, kp, RowP, ColP);
  loss_kernel<<<32, 256, 0, stream>>>(diag, RowP, ColP, out);
}

// Round 19
// 43.129 us; speedup vs baseline: 1.0101x; 1.0101x over previous
//
#include <hip/hip_runtime.h>
#include <hip/hip_bf16.h>

// SelfContrastiveLoss: loss over E = exp(qn @ kn^T / T), B=8192, D=256.
// R19: consolidation. GEMM + loss = R17 verbatim (best: 42.98us total; R18's
//      flip-stream was flat -> R17 structure is the GEMM frontier).
//      norm_pack restructured: 256 blocks (1/CU) x 1024 thr, 32 rows/block;
//      phase 1 = 2 rows/wave, phase 2 = all 1024 threads write (was 512/1024
//      idle). Halves the kernel's wave-slots at same traffic.
//
// ws layout: qp 2MB | kp 2MB | diag 32KB | RowP 1MB | ColP 2MB

#define NB 8192
#define ND 256

constexpr float EPS = 1e-5f;
// exp(x*20) == exp2(x * 20*log2(e))
constexpr float EXP2_SCALE = 28.853900817779268f;

typedef float f32x4 __attribute__((ext_vector_type(4)));
typedef int   i32x8 __attribute__((ext_vector_type(8)));

__device__ __forceinline__ float fast_exp2(float x) {
  float r;
  asm("v_exp_f32 %0, %1" : "=v"(r) : "v"(x));   // exact for |x| <= 126
  return r;
}

// packed layout (per 16-row group g, per matrix): 32B unit (ks, lane):
//   row g*16 + (lane&15), K-bytes ks*128 + (lane>>4)*32 .. +32, CONTIGUOUS.
// byte address = g*4096 + ks*2048 + lane*32.

// ------------- kernel 1: L2-normalize -> fp8 e4m3 packed, fp32 diag ----------
// 256 blocks x 1024 threads; 32 rows/block (2 groups of 16).
__global__ __launch_bounds__(1024) void norm_pack_kernel(
    const float* __restrict__ q, const float* __restrict__ k,
    uint* __restrict__ qp, uint* __restrict__ kp, float* __restrict__ diag,
    float* __restrict__ out) {
  __shared__ uint lq[32 * 68];   // stride 68 dwords: breaks 64-stride banks
  __shared__ uint lk[32 * 68];
  if (blockIdx.x == 0 && threadIdx.x == 0) out[0] = 0.f;  // loss accumulator

  const int w    = threadIdx.x >> 6;          // 0..15
  const int lane = threadIdx.x & 63;
#pragma unroll
  for (int i = 0; i < 2; ++i) {
    const int lrow = w * 2 + i;               // 0..31 row-in-block
    const int row  = blockIdx.x * 32 + lrow;
    const float4* q4 = reinterpret_cast<const float4*>(q + (size_t)row * ND);
    const float4* k4 = reinterpret_cast<const float4*>(k + (size_t)row * ND);
    float4 qv = q4[lane];
    float4 kv = k4[lane];
    float sq = qv.x * qv.x + qv.y * qv.y + qv.z * qv.z + qv.w * qv.w;
    float sk = kv.x * kv.x + kv.y * kv.y + kv.z * kv.z + kv.w * kv.w;
    float dp = qv.x * kv.x + qv.y * kv.y + qv.z * kv.z + qv.w * kv.w;
#pragma unroll
    for (int m = 1; m < 64; m <<= 1) {
      sq += __shfl_xor(sq, m);
      sk += __shfl_xor(sk, m);
      dp += __shfl_xor(dp, m);
    }
    const float iq = 1.0f / fmaxf(sqrtf(sq), 1e-12f);   // F.normalize eps
    const float ik = 1.0f / fmaxf(sqrtf(sk), 1e-12f);
    int dq = __builtin_amdgcn_cvt_pk_fp8_f32(qv.x * iq, qv.y * iq, 0, false);
    dq = __builtin_amdgcn_cvt_pk_fp8_f32(qv.z * iq, qv.w * iq, dq, true);
    int dk = __builtin_amdgcn_cvt_pk_fp8_f32(kv.x * ik, kv.y * ik, 0, false);
    dk = __builtin_amdgcn_cvt_pk_fp8_f32(kv.z * ik, kv.w * ik, dk, true);
    lq[lrow * 68 + lane] = (uint)dq;
    lk[lrow * 68 + lane] = (uint)dk;
    if (lane == 0) diag[row] = __expf(dp * iq * ik * 20.0f);  // exact fp32 diag
  }
  __syncthreads();

  // packed write: ALL 1024 threads; 2 groups x 2 matrices x 256 uint4.
  const int t   = threadIdx.x;
  const int idx = t & 511;
  const int grp = idx >> 8;           // 0/1: which 16-row group
  const int tt  = idx & 255;
  const int u   = tt >> 1;            // unit 0..127 (= ks*64 + ul)
  const int h   = tt & 1;             // 16B half
  const int ul  = u & 63;
  const int ks  = u >> 6;
  const int src_dw = (grp * 16 + (ul & 15)) * 68 + ks * 32 + (ul >> 4) * 8 + h * 4;
  const uint* Ls = (t < 512) ? lq : lk;
  uint4 v = *reinterpret_cast<const uint4*>(&Ls[src_dw]);
  uint* dst = (t < 512) ? qp : kp;
  reinterpret_cast<uint4*>(dst)[(size_t)(blockIdx.x * 2 + grp) * 256 + tt] = v;
}

// ------------- kernel 2: MX-fp8 MFMA GEMM (transposed) + exp + partials ------
// R17 verbatim. Tile 128q x 256k, 4 waves (2 q-half x 2 k-half), wave-tile
// 64q x 128k. TRANSPOSED: acc = mfma(K, Q) -> at lane (l15,lhi), (kg,qg), j2:
//   S[qrow = brow+wr*64+qg*16+l15][kcol = bcol+wc*128+kg*16+lhi*4+j2]
#define BTQ 128
#define BTK 256

__global__ __launch_bounds__(256, 2) void gemm_exp_reduce_kernel(
    const uint* __restrict__ qp, const uint* __restrict__ kp,
    float* __restrict__ RowP, float* __restrict__ ColP) {
  __shared__ float RS[128 * 3];   // row partials by wc (2 used)
  __shared__ float CS[256 * 3];   // col partials by wr (2 used)

  const int tid  = threadIdx.x;
  const int lane = tid & 63;
  const int wave = tid >> 6;
  const int wr = wave >> 1;           // 0..1  (64 q-rows)
  const int wc = wave & 1;            // 0..1  (128 k-cols)
  const int l15 = lane & 15;
  const int lhi = lane >> 4;

  // XCD-region map: 2048 blocks (64 rb x 32 cb); region 32rb x 8cb (~1.5MB)
  const int lid = blockIdx.y * 32 + blockIdx.x;
  const int xcd = lid & 7;
  const int j   = lid >> 3;                       // 0..255
  const int rb  = (xcd >> 2) * 32 + (j >> 3);     // row-block 0..63
  const int cb  = (xcd & 3) * 8 + (j & 7);        // col-block 0..31
  const int brow = rb * BTQ;
  const int bcol = cb * BTK;

  const i32x8* qp8 = reinterpret_cast<const i32x8*>(qp);
  const i32x8* kp8 = reinterpret_cast<const i32x8*>(kp);
  // i32x8 index: g*128 + ks*64 + lane
  const int qg0 = (brow >> 4) + wr * 4;   // 4 q-groups for this wave
  const int kg0 = (bcol >> 4) + wc * 8;   // 8 k-groups

  f32x4 acc[8][4];   // [kg][qg]
#pragma unroll
  for (int kg = 0; kg < 8; ++kg)
#pragma unroll
    for (int qg = 0; qg < 4; ++qg)
      acc[kg][qg] = (f32x4){0.f, 0.f, 0.f, 0.f};

  // ks outer: hold 8 K-frags + 1 Q-frag live; peak regs ~200
#pragma unroll
  for (int ks = 0; ks < 2; ++ks) {
    i32x8 kf[8];
#pragma unroll
    for (int kg = 0; kg < 8; ++kg)
      kf[kg] = kp8[(size_t)(kg0 + kg) * 128 + ks * 64 + lane];
#pragma unroll
    for (int qg = 0; qg < 4; ++qg) {
      const i32x8 qf = qp8[(size_t)(qg0 + qg) * 128 + ks * 64 + lane];
#pragma unroll
      for (int kg = 0; kg < 8; ++kg)
        // fp8 x fp8, unity e8m0 scales (0x7F = 2^0); A=K, B=Q (transposed)
        acc[kg][qg] = __builtin_amdgcn_mfma_scale_f32_16x16x128_f8f6f4(
            kf[kg], qf, acc[kg][qg], 0, 0, 0, 0x7F7F7F7F, 0, 0x7F7F7F7F);
    }
  }

  // ---- E = exp2(S*scale): raw v_exp_f32, 2 VALU/element ----
#pragma unroll
  for (int kg = 0; kg < 8; ++kg)
#pragma unroll
    for (int qg = 0; qg < 4; ++qg)
#pragma unroll
      for (int j2 = 0; j2 < 4; ++j2)
        acc[kg][qg][j2] = fast_exp2(acc[kg][qg][j2] * EXP2_SCALE);

  // ---- rowsums (q-rows): in-thread over kg,j2 (31 adds), fold over lhi ----
  float rs[4];
#pragma unroll
  for (int qg = 0; qg < 4; ++qg) {
    f32x4 s4 = ((acc[0][qg] + acc[1][qg]) + (acc[2][qg] + acc[3][qg])) +
               ((acc[4][qg] + acc[5][qg]) + (acc[6][qg] + acc[7][qg]));
    float v = (s4[0] + s4[1]) + (s4[2] + s4[3]);
    v += __shfl_xor(v, 16);
    v += __shfl_xor(v, 32);
    rs[qg] = v;   // full 128-col sum for row (qg, l15), replicated over lhi
  }
  {
    float val = (lhi == 0) ? rs[0] : (lhi == 1) ? rs[1] : (lhi == 2) ? rs[2] : rs[3];
    RS[(wr * 64 + lhi * 16 + l15) * 3 + wc] = val;
  }

  // ---- colsums: in-thread over qg, then fold; 2 kcol results per lane ----
  float c[8][4];
#pragma unroll
  for (int kg = 0; kg < 8; ++kg)
#pragma unroll
    for (int j2 = 0; j2 < 4; ++j2)
      c[kg][j2] = (acc[kg][0][j2] + acc[kg][1][j2]) +
                  (acc[kg][2][j2] + acc[kg][3][j2]);
  const bool b0 = (l15 & 1), b1 = (l15 & 2), b2 = (l15 & 4), b3 = (l15 & 8);
  // stage 1 (xor 1): fold j2 bit0 -> d[kg][jh]
  float d[8][2];
#pragma unroll
  for (int kg = 0; kg < 8; ++kg) {
#pragma unroll
    for (int jh = 0; jh < 2; ++jh) {
      float t = b0 ? c[kg][jh * 2] : c[kg][jh * 2 + 1];
      float u = __shfl_xor(t, 1);
      d[kg][jh] = (b0 ? c[kg][jh * 2 + 1] : c[kg][jh * 2]) + u;
    }
  }
  // stage 2 (xor 2): fold j2 bit1 -> e[kg]
  float e[8];
#pragma unroll
  for (int kg = 0; kg < 8; ++kg) {
    float t = b1 ? d[kg][0] : d[kg][1];
    float u = __shfl_xor(t, 2);
    e[kg] = (b1 ? d[kg][1] : d[kg][0]) + u;
  }
  // stage 3 (xor 4): fold kg bit0 -> g[4]
  float g[4];
#pragma unroll
  for (int m = 0; m < 4; ++m) {
    float t = b2 ? e[2 * m] : e[2 * m + 1];
    float u = __shfl_xor(t, 4);
    g[m] = (b2 ? e[2 * m + 1] : e[2 * m]) + u;
  }
  // stage 4 (xor 8): fold kg bit1 -> h0,h1
  float h0, h1;
  {
    float t, u;
    t = b3 ? g[0] : g[1]; u = __shfl_xor(t, 8); h0 = (b3 ? g[1] : g[0]) + u;
    t = b3 ? g[2] : g[3]; u = __shfl_xor(t, 8); h1 = (b3 ? g[3] : g[2]) + u;
  }
  // lane holds kg = n*4 + ((l15>>2)&3), j2 = l15&3, for n = 0 (h0), 1 (h1)
  {
    const int base = wc * 128 + ((l15 >> 2) & 3) * 16 + lhi * 4 + (l15 & 3);
    CS[(base) * 3 + wr] = h0;
    CS[(base + 64) * 3 + wr] = h1;
  }
  __syncthreads();

  if (tid < 128) {
    RowP[(size_t)cb * NB + brow + tid] = RS[tid * 3 + 0] + RS[tid * 3 + 1];
  } else {
    const int t = tid - 128;        // 0..127, handles cols t and t+128
    ColP[(size_t)rb * NB + bcol + t] = CS[t * 3 + 0] + CS[t * 3 + 1];
    ColP[(size_t)rb * NB + bcol + t + 128] =
        CS[(t + 128) * 3 + 0] + CS[(t + 128) * 3 + 1];
  }
}

// ---------------- kernel 3: sum partials + final scalar loss ----------------
// RowP has 32 partials per row (32 col-blocks); ColP has 64 (64 row-blocks).
__global__ __launch_bounds__(256) void loss_kernel(
    const float* __restrict__ diag, const float* __restrict__ RowP,
    const float* __restrict__ ColP, float* __restrict__ out) {
  const int i = blockIdx.x * 256 + threadIdx.x;   // 32 blocks x 256 = 8192
  float rs = 0.f, cs = 0.f;
#pragma unroll 8
  for (int j = 0; j < 32; ++j) rs += RowP[(size_t)j * NB + i];
#pragma unroll 8
  for (int j = 0; j < 64; ++j) cs += ColP[(size_t)j * NB + i];
  const float d = diag[i];
  float acc = -__logf(d / rs + EPS) - __logf(d / cs + EPS);
#pragma unroll
  for (int m = 1; m < 64; m <<= 1) acc += __shfl_xor(acc, m);
  __shared__ float ls[4];
  const int wave = threadIdx.x >> 6;
  if ((threadIdx.x & 63) == 0) ls[wave] = acc;
  __syncthreads();
  if (threadIdx.x == 0)
    atomicAdd(out, (ls[0] + ls[1] + ls[2] + ls[3]) * (1.0f / NB));
}

extern "C" void kernel_launch(void* const* d_in, const int* in_sizes, int n_in,
                              void* d_out, int out_size, void* d_ws, size_t ws_size,
                              hipStream_t stream) {
  const float* q = (const float*)d_in[0];
  const float* k = (const float*)d_in[1];
  char* ws = (char*)d_ws;
  uint*  qp   = (uint*)ws;                                      // 2 MB packed
  uint*  kp   = (uint*)(ws + (size_t)NB * ND);                  // 2 MB packed
  float* diag = (float*)(ws + (size_t)2 * NB * ND);             // 32 KB
  float* RowP = diag + NB;                                      // 1 MB (32*NB)
  float* ColP = RowP + 32 * NB;                                 // 2 MB (64*NB)
  float* out  = (float*)d_out;

  norm_pack_kernel<<<NB / 32, 1024, 0, stream>>>(q, k, qp, kp, diag, out);
  gemm_exp_reduce_kernel<<<dim3(32, 64), 256, 0, stream>>>(qp, kp, RowP, ColP);
  loss_kernel<<<32, 256, 0, stream>>>(diag, RowP, ColP, out);
}

// Round 20
// 41.648 us; speedup vs baseline: 1.0461x; 1.0356x over previous
//
#include <hip/hip_runtime.h>
#include <hip/hip_bf16.h>

// SelfContrastiveLoss: loss over E = exp(qn @ kn^T / T), B=8192, D=256.
// R20: R17 verbatim + fold the exp2-scale (28.8539) into the MX machinery:
//      scale_a = 0x84 (2^5, HW-applied in the scaled MFMA) and qn pre-scaled
//      by 28.8539/32 = 0.901684 at quantization (free: folded into iq).
//      Epilogue becomes a bare v_exp_f32 per element (was mul+exp) — removes
//      67.1M v_mul_f32 and shortens the exp dependency chain. Diag path
//      unchanged (exact fp32, unscaled).
//
// ws layout: qp 2MB | kp 2MB | diag 32KB | RowP 1MB | ColP 2MB

#define NB 8192
#define ND 256

constexpr float EPS = 1e-5f;
// qn pre-scale: exp(x*20) = exp2(x * 28.8539); 28.8539 = 0.901684 * 2^5,
// with the 2^5 applied by the MFMA block-scale (scale_a byte 0x84).
constexpr float Q_PRESCALE = 0.90168440055560214f;   // 28.8539.../32

typedef float f32x4 __attribute__((ext_vector_type(4)));
typedef int   i32x8 __attribute__((ext_vector_type(8)));

__device__ __forceinline__ float fast_exp2(float x) {
  float r;
  asm("v_exp_f32 %0, %1" : "=v"(r) : "v"(x));   // exact for |x| <= 126
  return r;
}

// packed layout (per 16-row group g, per matrix): 32B unit (ks, lane):
//   row g*16 + (lane&15), K-bytes ks*128 + (lane>>4)*32 .. +32, CONTIGUOUS.
// byte address = g*4096 + ks*2048 + lane*32.

// ------------- kernel 1: L2-normalize -> fp8 e4m3 packed, fp32 diag ----------
__global__ __launch_bounds__(1024) void norm_pack_kernel(
    const float* __restrict__ q, const float* __restrict__ k,
    uint* __restrict__ qp, uint* __restrict__ kp, float* __restrict__ diag,
    float* __restrict__ out) {
  __shared__ uint lq[16 * 68];   // stride 68 dwords: breaks 64-stride banks
  __shared__ uint lk[16 * 68];
  if (blockIdx.x == 0 && threadIdx.x == 0) out[0] = 0.f;  // loss accumulator

  const int w    = threadIdx.x >> 6;          // 0..15 row-in-group
  const int lane = threadIdx.x & 63;
  const int row  = blockIdx.x * 16 + w;
  const float4* q4 = reinterpret_cast<const float4*>(q + (size_t)row * ND);
  const float4* k4 = reinterpret_cast<const float4*>(k + (size_t)row * ND);
  float4 qv = q4[lane];
  float4 kv = k4[lane];
  float sq = qv.x * qv.x + qv.y * qv.y + qv.z * qv.z + qv.w * qv.w;
  float sk = kv.x * kv.x + kv.y * kv.y + kv.z * kv.z + kv.w * kv.w;
  float dp = qv.x * kv.x + qv.y * kv.y + qv.z * kv.z + qv.w * kv.w;
#pragma unroll
  for (int m = 1; m < 64; m <<= 1) {
    sq += __shfl_xor(sq, m);
    sk += __shfl_xor(sk, m);
    dp += __shfl_xor(dp, m);
  }
  const float iq = 1.0f / fmaxf(sqrtf(sq), 1e-12f);   // F.normalize eps
  const float ik = 1.0f / fmaxf(sqrtf(sk), 1e-12f);
  const float iqs = iq * Q_PRESCALE;   // quantization-only prescale (q side)
  int dq = __builtin_amdgcn_cvt_pk_fp8_f32(qv.x * iqs, qv.y * iqs, 0, false);
  dq = __builtin_amdgcn_cvt_pk_fp8_f32(qv.z * iqs, qv.w * iqs, dq, true);
  int dk = __builtin_amdgcn_cvt_pk_fp8_f32(kv.x * ik, kv.y * ik, 0, false);
  dk = __builtin_amdgcn_cvt_pk_fp8_f32(kv.z * ik, kv.w * ik, dk, true);
  lq[w * 68 + lane] = (uint)dq;
  lk[w * 68 + lane] = (uint)dk;
  if (lane == 0) diag[row] = __expf(dp * iq * ik * 20.0f);  // exact fp32 diag
  __syncthreads();

  // packed write: thread t<512 handles one 16B half of one 32B unit.
  const int t = threadIdx.x;
  if (t < 512) {
    const int tt = t & 255;
    const int u  = tt >> 1;           // unit 0..127 (= ks*64 + lane)
    const int h  = tt & 1;            // 16B half
    const int ul = u & 63;            // unit lane
    const int ks = u >> 6;
    const int src_dw = (ul & 15) * 68 + ks * 32 + (ul >> 4) * 8 + h * 4;
    const uint* Ls = (t < 256) ? lq : lk;
    uint4 v = *reinterpret_cast<const uint4*>(&Ls[src_dw]);
    uint* dst = (t < 256) ? qp : kp;
    reinterpret_cast<uint4*>(dst)[(size_t)blockIdx.x * 256 + tt] = v;
  }
}

// ------------- kernel 2: MX-fp8 MFMA GEMM (transposed) + exp + partials ------
// Tile 128q x 256k, 4 waves (2 q-half x 2 k-half), wave-tile 64q x 128k.
// TRANSPOSED compute: acc = mfma(K, Q) -> at lane (l15,lhi), frag (kg,qg), j2:
//   S[qrow = brow+wr*64+qg*16+l15][kcol = bcol+wc*128+kg*16+lhi*4+j2]
// scale_a = 0x84 (2^5): acc arrives as 28.8539 * cos-sim (with Q_PRESCALE).
#define BTQ 128
#define BTK 256

__global__ __launch_bounds__(256, 2) void gemm_exp_reduce_kernel(
    const uint* __restrict__ qp, const uint* __restrict__ kp,
    float* __restrict__ RowP, float* __restrict__ ColP) {
  __shared__ float RS[128 * 3];   // row partials by wc (2 used)
  __shared__ float CS[256 * 3];   // col partials by wr (2 used)

  const int tid  = threadIdx.x;
  const int lane = tid & 63;
  const int wave = tid >> 6;
  const int wr = wave >> 1;           // 0..1  (64 q-rows)
  const int wc = wave & 1;            // 0..1  (128 k-cols)
  const int l15 = lane & 15;
  const int lhi = lane >> 4;

  // XCD-region map: 2048 blocks (64 rb x 32 cb); region 32rb x 8cb (~1.5MB)
  const int lid = blockIdx.y * 32 + blockIdx.x;
  const int xcd = lid & 7;
  const int j   = lid >> 3;                       // 0..255
  const int rb  = (xcd >> 2) * 32 + (j >> 3);     // row-block 0..63
  const int cb  = (xcd & 3) * 8 + (j & 7);        // col-block 0..31
  const int brow = rb * BTQ;
  const int bcol = cb * BTK;

  const i32x8* qp8 = reinterpret_cast<const i32x8*>(qp);
  const i32x8* kp8 = reinterpret_cast<const i32x8*>(kp);
  // i32x8 index: g*128 + ks*64 + lane
  const int qg0 = (brow >> 4) + wr * 4;   // 4 q-groups for this wave
  const int kg0 = (bcol >> 4) + wc * 8;   // 8 k-groups

  f32x4 acc[8][4];   // [kg][qg]
#pragma unroll
  for (int kg = 0; kg < 8; ++kg)
#pragma unroll
    for (int qg = 0; qg < 4; ++qg)
      acc[kg][qg] = (f32x4){0.f, 0.f, 0.f, 0.f};

  // ks outer: hold 8 K-frags + 1 Q-frag live; peak regs ~200
#pragma unroll
  for (int ks = 0; ks < 2; ++ks) {
    i32x8 kf[8];
#pragma unroll
    for (int kg = 0; kg < 8; ++kg)
      kf[kg] = kp8[(size_t)(kg0 + kg) * 128 + ks * 64 + lane];
#pragma unroll
    for (int qg = 0; qg < 4; ++qg) {
      const i32x8 qf = qp8[(size_t)(qg0 + qg) * 128 + ks * 64 + lane];
#pragma unroll
      for (int kg = 0; kg < 8; ++kg)
        // fp8 x fp8; scale_a = 2^5 (0x84), scale_b = 2^0 (0x7F); A=K, B=Q
        acc[kg][qg] = __builtin_amdgcn_mfma_scale_f32_16x16x128_f8f6f4(
            kf[kg], qf, acc[kg][qg], 0, 0, 0, 0x84848484, 0, 0x7F7F7F7F);
    }
  }

  // ---- E = exp2(acc): bare v_exp_f32 (scale already applied by HW) ----
#pragma unroll
  for (int kg = 0; kg < 8; ++kg)
#pragma unroll
    for (int qg = 0; qg < 4; ++qg)
#pragma unroll
      for (int j2 = 0; j2 < 4; ++j2)
        acc[kg][qg][j2] = fast_exp2(acc[kg][qg][j2]);

  // ---- rowsums (q-rows): in-thread over kg,j2 (31 adds), fold over lhi ----
  float rs[4];
#pragma unroll
  for (int qg = 0; qg < 4; ++qg) {
    f32x4 s4 = ((acc[0][qg] + acc[1][qg]) + (acc[2][qg] + acc[3][qg])) +
               ((acc[4][qg] + acc[5][qg]) + (acc[6][qg] + acc[7][qg]));
    float v = (s4[0] + s4[1]) + (s4[2] + s4[3]);
    v += __shfl_xor(v, 16);
    v += __shfl_xor(v, 32);
    rs[qg] = v;   // full 128-col sum for row (qg, l15), replicated over lhi
  }
  {
    float val = (lhi == 0) ? rs[0] : (lhi == 1) ? rs[1] : (lhi == 2) ? rs[2] : rs[3];
    RS[(wr * 64 + lhi * 16 + l15) * 3 + wc] = val;
  }

  // ---- colsums: in-thread over qg, then fold; 2 kcol results per lane ----
  float c[8][4];
#pragma unroll
  for (int kg = 0; kg < 8; ++kg)
#pragma unroll
    for (int j2 = 0; j2 < 4; ++j2)
      c[kg][j2] = (acc[kg][0][j2] + acc[kg][1][j2]) +
                  (acc[kg][2][j2] + acc[kg][3][j2]);
  const bool b0 = (l15 & 1), b1 = (l15 & 2), b2 = (l15 & 4), b3 = (l15 & 8);
  // stage 1 (xor 1): fold j2 bit0 -> d[kg][jh]
  float d[8][2];
#pragma unroll
  for (int kg = 0; kg < 8; ++kg) {
#pragma unroll
    for (int jh = 0; jh < 2; ++jh) {
      float t = b0 ? c[kg][jh * 2] : c[kg][jh * 2 + 1];
      float u = __shfl_xor(t, 1);
      d[kg][jh] = (b0 ? c[kg][jh * 2 + 1] : c[kg][jh * 2]) + u;
    }
  }
  // stage 2 (xor 2): fold j2 bit1 -> e[kg]
  float e[8];
#pragma unroll
  for (int kg = 0; kg < 8; ++kg) {
    float t = b1 ? d[kg][0] : d[kg][1];
    float u = __shfl_xor(t, 2);
    e[kg] = (b1 ? d[kg][1] : d[kg][0]) + u;
  }
  // stage 3 (xor 4): fold kg bit0 -> g[4]
  float g[4];
#pragma unroll
  for (int m = 0; m < 4; ++m) {
    float t = b2 ? e[2 * m] : e[2 * m + 1];
    float u = __shfl_xor(t, 4);
    g[m] = (b2 ? e[2 * m + 1] : e[2 * m]) + u;
  }
  // stage 4 (xor 8): fold kg bit1 -> h0,h1
  float h0, h1;
  {
    float t, u;
    t = b3 ? g[0] : g[1]; u = __shfl_xor(t, 8); h0 = (b3 ? g[1] : g[0]) + u;
    t = b3 ? g[2] : g[3]; u = __shfl_xor(t, 8); h1 = (b3 ? g[3] : g[2]) + u;
  }
  // lane holds kg = n*4 + ((l15>>2)&3), j2 = l15&3, for n = 0 (h0), 1 (h1)
  {
    const int base = wc * 128 + ((l15 >> 2) & 3) * 16 + lhi * 4 + (l15 & 3);
    CS[(base) * 3 + wr] = h0;
    CS[(base + 64) * 3 + wr] = h1;
  }
  __syncthreads();

  if (tid < 128) {
    RowP[(size_t)cb * NB + brow + tid] = RS[tid * 3 + 0] + RS[tid * 3 + 1];
  } else {
    const int t = tid - 128;        // 0..127, handles cols t and t+128
    ColP[(size_t)rb * NB + bcol + t] = CS[t * 3 + 0] + CS[t * 3 + 1];
    ColP[(size_t)rb * NB + bcol + t + 128] =
        CS[(t + 128) * 3 + 0] + CS[(t + 128) * 3 + 1];
  }
}

// ---------------- kernel 3: sum partials + final scalar loss ----------------
// RowP has 32 partials per row (32 col-blocks); ColP has 64 (64 row-blocks).
__global__ __launch_bounds__(256) void loss_kernel(
    const float* __restrict__ diag, const float* __restrict__ RowP,
    const float* __restrict__ ColP, float* __restrict__ out) {
  const int i = blockIdx.x * 256 + threadIdx.x;   // 32 blocks x 256 = 8192
  float rs = 0.f, cs = 0.f;
#pragma unroll 8
  for (int j = 0; j < 32; ++j) rs += RowP[(size_t)j * NB + i];
#pragma unroll 8
  for (int j = 0; j < 64; ++j) cs += ColP[(size_t)j * NB + i];
  const float d = diag[i];
  float acc = -__logf(d / rs + EPS) - __logf(d / cs + EPS);
#pragma unroll
  for (int m = 1; m < 64; m <<= 1) acc += __shfl_xor(acc, m);
  __shared__ float ls[4];
  const int wave = threadIdx.x >> 6;
  if ((threadIdx.x & 63) == 0) ls[wave] = acc;
  __syncthreads();
  if (threadIdx.x == 0)
    atomicAdd(out, (ls[0] + ls[1] + ls[2] + ls[3]) * (1.0f / NB));
}

extern "C" void kernel_launch(void* const* d_in, const int* in_sizes, int n_in,
                              void* d_out, int out_size, void* d_ws, size_t ws_size,
                              hipStream_t stream) {
  const float* q = (const float*)d_in[0];
  const float* k = (const float*)d_in[1];
  char* ws = (char*)d_ws;
  uint*  qp   = (uint*)ws;                                      // 2 MB packed
  uint*  kp   = (uint*)(ws + (size_t)NB * ND);                  // 2 MB packed
  float* diag = (float*)(ws + (size_t)2 * NB * ND);             // 32 KB
  float* RowP = diag + NB;                                      // 1 MB (32*NB)
  float* ColP = RowP + 32 * NB;                                 // 2 MB (64*NB)
  float* out  = (float*)d_out;

  norm_pack_kernel<<<NB / 16, 1024, 0, stream>>>(q, k, qp, kp, diag, out);
  gemm_exp_reduce_kernel<<<dim3(32, 64), 256, 0, stream>>>(qp, kp, RowP, ColP);
  loss_kernel<<<32, 256, 0, stream>>>(diag, RowP, ColP, out);
}